// Round 2
// baseline (1009.559 us; speedup 1.0000x reference)
//
#include <hip/hip_runtime.h>
#include <stdint.h>

typedef __attribute__((ext_vector_type(8))) short short8;
typedef __attribute__((ext_vector_type(4))) float f32x4;

__device__ __forceinline__ ushort f2bf(float f) {
    uint u = __float_as_uint(f);
    u += 0x7FFF + ((u >> 16) & 1);
    return (ushort)(u >> 16);
}

// async global->LDS, 16B per lane; LDS dest must be wave-uniform-base + lane*16
#define GLDS16(g, l)                                                  \
    __builtin_amdgcn_global_load_lds(                                 \
        (__attribute__((address_space(1))) void*)(g),                 \
        (__attribute__((address_space(3))) void*)(l), 16, 0, 0)

// ---------------- prep: all weights -> bf16 / gathered layouts ----------------
// sections: prewb(589824) | postwb(589824) | wcat(786432) | wcat2(98304)
__global__ void prep_w(const float* __restrict__ pre_w, const float* __restrict__ post_w,
                       const float* __restrict__ wih_f, const float* __restrict__ whh_f,
                       const float* __restrict__ wih_b, const float* __restrict__ whh_b,
                       const float* __restrict__ head_w,
                       ushort* __restrict__ prewb, ushort* __restrict__ postwb,
                       ushort* __restrict__ wcat, ushort* __restrict__ wcat2) {
    int i = blockIdx.x * 256 + threadIdx.x;
    const int NW = 589824;
    if (i < NW) { prewb[i] = f2bf(pre_w[i]); return; }
    i -= NW;
    if (i < NW) { postwb[i] = f2bf(post_w[i]); return; }
    i -= NW;
    if (i < 786432) {  // wcat [(d*12+h)*256+n][128]: k<64 -> wih, else whh
        int k = i & 127, n = (i >> 7) & 255, dh = i >> 15;
        int d = dh / 12, h = dh % 12;
        int gr = (n >> 6) * 768 + h * 64 + (n & 63);
        const float* wih = d ? wih_b : wih_f;
        const float* whh = d ? whh_b : whh_f;
        float v = (k < 64) ? wih[gr * 768 + h * 64 + k] : whh[gr * 768 + h * 64 + (k - 64)];
        wcat[i] = f2bf(v); return;
    }
    i -= 786432;
    {   // wcat2 [h*64+n][128]: k<64 fwd half, else bwd half
        int k = i & 127, n = (i >> 7) & 63, h = i >> 13;
        int row = h * 64 + n;
        float v = (k < 64) ? head_w[row * 1536 + h * 64 + k]
                           : head_w[row * 1536 + 768 + h * 64 + (k - 64)];
        wcat2[i] = f2bf(v);
    }
}

// ---------------- GEMM: C[32768,768] = A[32768,768] @ Bt[768,768]^T + bias ----------------
// tile 128x128, BK=64, 4 waves each 64x64 (m97 structure). INF32: A is f32, fused cvt.
template<int INF32, int OUTBF>
__global__ __launch_bounds__(256) void gemm_bt(const void* __restrict__ Ain,
                                               const ushort* __restrict__ Bt,
                                               const float* __restrict__ bias,
                                               void* __restrict__ out) {
    __shared__ __align__(16) ushort sA[128 * 64];
    __shared__ __align__(16) ushort sB[128 * 64];
    int t = threadIdx.x;
    int m0 = blockIdx.x * 128, n0 = blockIdx.y * 128;
    int w = t >> 6, l = t & 63, r = l & 15, q = l >> 4;
    int wm = w >> 1, wn = w & 1;
    f32x4 acc[4][4];
#pragma unroll
    for (int a = 0; a < 4; ++a)
#pragma unroll
        for (int b = 0; b < 4; ++b) acc[a][b] = (f32x4){0.f, 0.f, 0.f, 0.f};

    for (int kt = 0; kt < 12; ++kt) {
        int k0 = kt * 64;
        __syncthreads();   // previous tile's LDS reads must finish before restage
#pragma unroll
        for (int i = 0; i < 4; ++i) {   // B: async direct to LDS (linear dest = c*16B)
            int c = t + i * 256, row = c >> 3, col = (c & 7) * 8;
            GLDS16(&Bt[(size_t)(n0 + row) * 768 + k0 + col], &sB[row * 64 + col]);
        }
        if (INF32) {
#pragma unroll
            for (int i = 0; i < 4; ++i) {  // A: f32 load + cvt + ds_write (fused prep)
                int c = t + i * 256, row = c >> 3, col = (c & 7) * 8;
                const float* ap = (const float*)Ain + (size_t)(m0 + row) * 768 + k0 + col;
                float4 u0 = *(const float4*)ap;
                float4 u1 = *(const float4*)(ap + 4);
                short8 v;
                v[0] = (short)f2bf(u0.x); v[1] = (short)f2bf(u0.y);
                v[2] = (short)f2bf(u0.z); v[3] = (short)f2bf(u0.w);
                v[4] = (short)f2bf(u1.x); v[5] = (short)f2bf(u1.y);
                v[6] = (short)f2bf(u1.z); v[7] = (short)f2bf(u1.w);
                *(short8*)&sA[row * 64 + col] = v;
            }
        } else {
#pragma unroll
            for (int i = 0; i < 4; ++i) {
                int c = t + i * 256, row = c >> 3, col = (c & 7) * 8;
                GLDS16(&((const ushort*)Ain)[(size_t)(m0 + row) * 768 + k0 + col],
                       &sA[row * 64 + col]);
            }
        }
        __syncthreads();   // drains vmcnt (global_load_lds) + lgkm (ds_write)
#pragma unroll
        for (int kk = 0; kk < 2; ++kk) {
            short8 af[4], bf[4];
#pragma unroll
            for (int mt = 0; mt < 4; ++mt)
                af[mt] = *(const short8*)&sA[(wm * 64 + mt * 16 + r) * 64 + kk * 32 + q * 8];
#pragma unroll
            for (int nt = 0; nt < 4; ++nt)
                bf[nt] = *(const short8*)&sB[(wn * 64 + nt * 16 + r) * 64 + kk * 32 + q * 8];
#pragma unroll
            for (int mt = 0; mt < 4; ++mt)
#pragma unroll
                for (int nt = 0; nt < 4; ++nt)
                    acc[mt][nt] = __builtin_amdgcn_mfma_f32_16x16x32_bf16(af[mt], bf[nt], acc[mt][nt], 0, 0, 0);
        }
    }
#pragma unroll
    for (int nt = 0; nt < 4; ++nt) {
        int col = n0 + wn * 64 + nt * 16 + r;
        float bv = bias[col];
#pragma unroll
        for (int mt = 0; mt < 4; ++mt) {
            int rowb = m0 + wm * 64 + mt * 16 + q * 4;
#pragma unroll
            for (int j = 0; j < 4; ++j) {
                float v = acc[mt][nt][j] + bv;
                if (OUTBF) ((ushort*)out)[(size_t)(rowb + j) * 768 + col] = f2bf(v);
                else       ((float*)out)[(size_t)(rowb + j) * 768 + col] = v;
            }
        }
    }
}

// ---------------- recurrence: one WG per (dir, head, batch-quarter) ----------------
// 512 threads = 8 waves; wave w owns gate cols [w*32, w*32+32)
__global__ __launch_bounds__(512) void lstm_rec(const ushort* __restrict__ ybf,
                                                const ushort* __restrict__ wcat,
                                                const float* __restrict__ bih_f,
                                                const float* __restrict__ bhh_f,
                                                const float* __restrict__ bih_b,
                                                const float* __restrict__ bhh_b,
                                                ushort* __restrict__ hs) {
    __shared__ __align__(16) float gbuf[256 * 20];      // [n][b] padded to 20 (16B-aligned rows)
    __shared__ __align__(16) ushort hbuf[16 * 64];      // XOR-swizzled on 8-elem granules
    int t = threadIdx.x;
    int w = t >> 6, l = t & 63, r = l & 15, q = l >> 4;
    int b0 = blockIdx.x * 16, h = blockIdx.y, d = blockIdx.z;

    // B fragments (constant over all 512 steps) -> registers
    const ushort* wp = wcat + (size_t)(d * 12 + h) * 256 * 128;
    short8 bfr[2][4];
#pragma unroll
    for (int nt = 0; nt < 2; ++nt)
#pragma unroll
        for (int kk = 0; kk < 4; ++kk) {
            int n = w * 32 + nt * 16 + r, k = kk * 32 + q * 8;
            bfr[nt][kk] = *(const short8*)&wp[n * 128 + k];
        }
    // per-column gate bias -> MFMA C-init (col = n, same for all 4 rows of the frag)
    const float* bih = d ? bih_b : bih_f;
    const float* bhh = d ? bhh_b : bhh_f;
    float bv[2];
#pragma unroll
    for (int nt = 0; nt < 2; ++nt) {
        int n = w * 32 + nt * 16 + r;
        int gr = (n >> 6) * 768 + h * 64 + (n & 63);
        bv[nt] = bih[gr] + bhh[gr];
    }
    // per-thread update slots: batch row bl, gate cols 2*j2, 2*j2+1
    int bl = t & 15, j2 = t >> 4;
    float cst[2] = {0.f, 0.f};
    ((uint*)hbuf)[t] = 0u;  // zero h0 (512 uints = 1024 ushorts)

    const ushort* yrow = ybf + (size_t)(b0 + r) * 512 * 768 + h * 64 + q * 8;
    int s = d ? 511 : 0;
    int sstep = d ? -1 : 1;
    short8 yf0 = *(const short8*)&yrow[s * 768];
    short8 yf1 = *(const short8*)&yrow[s * 768 + 32];
    __syncthreads();

    for (int it = 0; it < 512; ++it) {
        short8 yc0 = yf0, yc1 = yf1;
        int snext = s + sstep;
        if (it < 511) {  // prefetch next step's A y-frags
            yf0 = *(const short8*)&yrow[snext * 768];
            yf1 = *(const short8*)&yrow[snext * 768 + 32];
        }
        // h fragments from swizzled LDS
        short8 ah0 = *(const short8*)&hbuf[r * 64 + ((q ^ (r & 7)) * 8)];
        short8 ah1 = *(const short8*)&hbuf[r * 64 + (((4 + q) ^ (r & 7)) * 8)];
        f32x4 acc[2];
#pragma unroll
        for (int nt = 0; nt < 2; ++nt) {
            f32x4 a = (f32x4){bv[nt], bv[nt], bv[nt], bv[nt]};
            a = __builtin_amdgcn_mfma_f32_16x16x32_bf16(yc0, bfr[nt][0], a, 0, 0, 0);
            a = __builtin_amdgcn_mfma_f32_16x16x32_bf16(yc1, bfr[nt][1], a, 0, 0, 0);
            a = __builtin_amdgcn_mfma_f32_16x16x32_bf16(ah0, bfr[nt][2], a, 0, 0, 0);
            a = __builtin_amdgcn_mfma_f32_16x16x32_bf16(ah1, bfr[nt][3], a, 0, 0, 0);
            acc[nt] = a;
        }
        // gates -> LDS: D lane holds rows (batch) 4q..4q+3, col n
#pragma unroll
        for (int nt = 0; nt < 2; ++nt) {
            int n = w * 32 + nt * 16 + r;
            *(f32x4*)&gbuf[n * 20 + q * 4] = acc[nt];
        }
        __syncthreads();
        // elementwise update (gate order i,f,g,o); bias already in acc
        float hh[2];
#pragma unroll
        for (int jj = 0; jj < 2; ++jj) {
            int j = 2 * j2 + jj;
            float ip = gbuf[j * 20 + bl];
            float fp = gbuf[(64 + j) * 20 + bl];
            float gp = gbuf[(128 + j) * 20 + bl];
            float op = gbuf[(192 + j) * 20 + bl];
            float ig = 1.f / (1.f + __expf(-ip));
            float fg = 1.f / (1.f + __expf(-fp));
            float gg = 2.f / (1.f + __expf(-2.f * gp)) - 1.f;
            float og = 1.f / (1.f + __expf(-op));
            float c = fg * cst[jj] + ig * gg;
            cst[jj] = c;
            float th = 2.f / (1.f + __expf(-2.f * c)) - 1.f;
            hh[jj] = og * th;
        }
        {   // h -> swizzled LDS (pair of bf16 = one u32)
            int j0 = 2 * j2, g8 = j0 >> 3;
            uint pk = (uint)f2bf(hh[0]) | ((uint)f2bf(hh[1]) << 16);
            *(uint*)&hbuf[bl * 64 + ((g8 ^ (bl & 7)) * 8 + (j0 & 7))] = pk;
        }
        __syncthreads();
        // coalesced hs write: 16 rows x 128B
        if (t < 256) {
            int rr = t >> 4, c16 = t & 15;
            int jj0 = c16 * 4, gg8 = c16 >> 1;
            uint2 v = *(const uint2*)&hbuf[rr * 64 + ((gg8 ^ (rr & 7)) * 8 + (jj0 & 7))];
            *(uint2*)&hs[((size_t)(b0 + rr) * 512 + s) * 1536 + d * 768 + h * 64 + jj0] = v;
        }
        s = snext;
    }
}

// ---------------- head projection: per-head [32768,128] @ [64,128]^T ----------------
__global__ __launch_bounds__(256) void head_proj(const ushort* __restrict__ hs,
                                                 const ushort* __restrict__ wcat2,
                                                 const float* __restrict__ head_b,
                                                 float* __restrict__ out2,
                                                 ushort* __restrict__ out1b) {
    __shared__ __align__(16) ushort sA[128 * 128];
    __shared__ __align__(16) ushort sB[64 * 128];
    int t = threadIdx.x;
    int h = blockIdx.y, m0 = blockIdx.x * 128;
#pragma unroll
    for (int i = 0; i < 8; ++i) {  // A: 128 rows x (fwd64|bwd64); LDS dest = c*16B linear
        int c = t + i * 256, row = c >> 4, c16 = c & 15;
        int dd = c16 >> 3, kc = (c16 & 7) * 8;
        GLDS16(&hs[(size_t)(m0 + row) * 1536 + dd * 768 + h * 64 + kc],
               &sA[row * 128 + c16 * 8]);
    }
#pragma unroll
    for (int i = 0; i < 4; ++i) {  // B: 64 rows x 128
        int c = t + i * 256, row = c >> 4, kc = (c & 15) * 8;
        GLDS16(&wcat2[(size_t)(h * 64 + row) * 128 + kc], &sB[row * 128 + kc]);
    }
    __syncthreads();
    int w = t >> 6, l = t & 63, r = l & 15, q = l >> 4;
    f32x4 acc[2][4];
#pragma unroll
    for (int a = 0; a < 2; ++a)
#pragma unroll
        for (int b = 0; b < 4; ++b) acc[a][b] = (f32x4){0.f, 0.f, 0.f, 0.f};
#pragma unroll
    for (int kk = 0; kk < 4; ++kk) {
        short8 af[2], bf[4];
#pragma unroll
        for (int mt = 0; mt < 2; ++mt)
            af[mt] = *(const short8*)&sA[(w * 32 + mt * 16 + r) * 128 + kk * 32 + q * 8];
#pragma unroll
        for (int nt = 0; nt < 4; ++nt)
            bf[nt] = *(const short8*)&sB[(nt * 16 + r) * 128 + kk * 32 + q * 8];
#pragma unroll
        for (int mt = 0; mt < 2; ++mt)
#pragma unroll
            for (int nt = 0; nt < 4; ++nt)
                acc[mt][nt] = __builtin_amdgcn_mfma_f32_16x16x32_bf16(af[mt], bf[nt], acc[mt][nt], 0, 0, 0);
    }
#pragma unroll
    for (int nt = 0; nt < 4; ++nt) {
        int colg = h * 64 + nt * 16 + r;
        float bvv = head_b[colg];
#pragma unroll
        for (int mt = 0; mt < 2; ++mt) {
            int rowb = m0 + w * 32 + mt * 16 + q * 4;
#pragma unroll
            for (int j = 0; j < 4; ++j) {
                float v = acc[mt][nt][j] + bvv;
                out2[(size_t)(rowb + j) * 768 + colg] = v;
                out1b[(size_t)(rowb + j) * 768 + colg] = f2bf(v);
            }
        }
    }
}

extern "C" void kernel_launch(void* const* d_in, const int* in_sizes, int n_in,
                              void* d_out, int out_size, void* d_ws, size_t ws_size,
                              hipStream_t stream) {
    const float* x      = (const float*)d_in[0];
    const float* pre_w  = (const float*)d_in[1];
    const float* pre_b  = (const float*)d_in[2];
    const float* wih_f  = (const float*)d_in[3];
    const float* whh_f  = (const float*)d_in[4];
    const float* bih_f  = (const float*)d_in[5];
    const float* bhh_f  = (const float*)d_in[6];
    const float* wih_b  = (const float*)d_in[7];
    const float* whh_b  = (const float*)d_in[8];
    const float* bih_b  = (const float*)d_in[9];
    const float* bhh_b  = (const float*)d_in[10];
    const float* head_w = (const float*)d_in[11];
    const float* head_b = (const float*)d_in[12];
    const float* post_w = (const float*)d_in[13];
    const float* post_b = (const float*)d_in[14];

    char* ws = (char*)d_ws;
    ushort* ybf    = (ushort*)(ws + 0);              // 50331648 B (reused as out1b later)
    ushort* hsb    = (ushort*)(ws + 50331648);       // 100663296 B
    ushort* wcat   = (ushort*)(ws + 150994944);      // 1572864 B
    ushort* wcat2  = (ushort*)(ws + 152567808);      // 196608 B
    ushort* prewb  = (ushort*)(ws + 152764416);      // 1179648 B
    ushort* postwb = (ushort*)(ws + 153944064);      // 1179648 B  (total 155123712 B)

    float* outp  = (float*)d_out;            // out:      [32768,768] f32
    float* out2p = outp + 25165824;          // lstm_out: [32768,768] f32
    ushort* out1b = ybf;                     // bf16 copy of lstm_out (alias; ybf dead)

    prep_w<<<dim3(8064), dim3(256), 0, stream>>>(pre_w, post_w, wih_f, whh_f,
                                                 wih_b, whh_b, head_w,
                                                 prewb, postwb, wcat, wcat2);
    gemm_bt<1, 1><<<dim3(256, 6), dim3(256), 0, stream>>>(x, prewb, pre_b, (void*)ybf);
    lstm_rec<<<dim3(4, 12, 2), dim3(512), 0, stream>>>(ybf, wcat, bih_f, bhh_f,
                                                       bih_b, bhh_b, hsb);
    head_proj<<<dim3(256, 12), dim3(256), 0, stream>>>(hsb, wcat2, head_b, out2p, out1b);
    gemm_bt<0, 0><<<dim3(256, 6), dim3(256), 0, stream>>>(out1b, postwb, post_b, (void*)outp);
}

// Round 8
// 860.468 us; speedup vs baseline: 1.1733x; 1.1733x over previous
//
#include <hip/hip_runtime.h>
#include <stdint.h>

typedef __attribute__((ext_vector_type(8))) short short8;
typedef __attribute__((ext_vector_type(4))) float f32x4;

#define MFMA __builtin_amdgcn_mfma_f32_16x16x32_bf16

__device__ __forceinline__ ushort f2bf(float f) {
    uint u = __float_as_uint(f);
    u += 0x7FFF + ((u >> 16) & 1);
    return (ushort)(u >> 16);
}
__device__ __forceinline__ float sigm(float x) {
    return __builtin_amdgcn_rcpf(1.f + __expf(-x));
}
__device__ __forceinline__ float tanh2(float x) {
    return 1.f - 2.f * __builtin_amdgcn_rcpf(1.f + __expf(2.f * x));
}

// async global->LDS, 16B per lane; LDS dest must be wave-uniform-base + lane*16
#define GLDS16(g, l)                                                  \
    __builtin_amdgcn_global_load_lds(                                 \
        (__attribute__((address_space(1))) void*)(g),                 \
        (__attribute__((address_space(3))) void*)(l), 16, 0, 0)

// ---------------- prep: all weights -> bf16 / gathered layouts ----------------
// sections: prewb(589824) | postwb(589824) | wcat(786432) | wcat2(98304)
// wcat column order is GATE-INTERLEAVED: n -> gate g = 2*((n>>4)&1) + ((n>>3)&1),
// hidden j = (n>>5)*8 + (n&7). Wave w = n>>5 owns hidden [8w,8w+8) x all 4 gates.
__global__ void prep_w(const float* __restrict__ pre_w, const float* __restrict__ post_w,
                       const float* __restrict__ wih_f, const float* __restrict__ whh_f,
                       const float* __restrict__ wih_b, const float* __restrict__ whh_b,
                       const float* __restrict__ head_w,
                       ushort* __restrict__ prewb, ushort* __restrict__ postwb,
                       ushort* __restrict__ wcat, ushort* __restrict__ wcat2) {
    int i = blockIdx.x * 256 + threadIdx.x;
    const int NW = 589824;
    if (i < NW) { prewb[i] = f2bf(pre_w[i]); return; }
    i -= NW;
    if (i < NW) { postwb[i] = f2bf(post_w[i]); return; }
    i -= NW;
    if (i < 786432) {  // wcat [(d*12+h)*256+n][128]: k<64 -> wih, else whh
        int k = i & 127, n = (i >> 7) & 255, dh = i >> 15;
        int d = dh / 12, h = dh % 12;
        int g = ((n >> 4) & 1) * 2 + ((n >> 3) & 1);
        int j = ((n >> 5) << 3) + (n & 7);
        int gr = g * 768 + h * 64 + j;
        const float* wih = d ? wih_b : wih_f;
        const float* whh = d ? whh_b : whh_f;
        float v = (k < 64) ? wih[gr * 768 + h * 64 + k] : whh[gr * 768 + h * 64 + (k - 64)];
        wcat[i] = f2bf(v); return;
    }
    i -= 786432;
    {   // wcat2 [h*64+n][128]: k<64 fwd half, else bwd half
        int k = i & 127, n = (i >> 7) & 63, h = i >> 13;
        int row = h * 64 + n;
        float v = (k < 64) ? head_w[row * 1536 + h * 64 + k]
                           : head_w[row * 1536 + 768 + h * 64 + (k - 64)];
        wcat2[i] = f2bf(v);
    }
}

// ---------------- GEMM: C[32768,768] = A[32768,768] @ Bt[768,768]^T + bias ----------------
template<int INF32, int OUTBF>
__global__ __launch_bounds__(256) void gemm_bt(const void* __restrict__ Ain,
                                               const ushort* __restrict__ Bt,
                                               const float* __restrict__ bias,
                                               void* __restrict__ out) {
    __shared__ __align__(16) ushort sA[128 * 64];
    __shared__ __align__(16) ushort sB[128 * 64];
    int t = threadIdx.x;
    int m0 = blockIdx.x * 128, n0 = blockIdx.y * 128;
    int w = t >> 6, l = t & 63, r = l & 15, q = l >> 4;
    int wm = w >> 1, wn = w & 1;
    f32x4 acc[4][4];
#pragma unroll
    for (int a = 0; a < 4; ++a)
#pragma unroll
        for (int b = 0; b < 4; ++b) acc[a][b] = (f32x4){0.f, 0.f, 0.f, 0.f};

    for (int kt = 0; kt < 12; ++kt) {
        int k0 = kt * 64;
        __syncthreads();
#pragma unroll
        for (int i = 0; i < 4; ++i) {
            int c = t + i * 256, row = c >> 3, col = (c & 7) * 8;
            GLDS16(&Bt[(size_t)(n0 + row) * 768 + k0 + col], &sB[row * 64 + col]);
        }
        if (INF32) {
#pragma unroll
            for (int i = 0; i < 4; ++i) {
                int c = t + i * 256, row = c >> 3, col = (c & 7) * 8;
                const float* ap = (const float*)Ain + (size_t)(m0 + row) * 768 + k0 + col;
                float4 u0 = *(const float4*)ap;
                float4 u1 = *(const float4*)(ap + 4);
                short8 v;
                v[0] = (short)f2bf(u0.x); v[1] = (short)f2bf(u0.y);
                v[2] = (short)f2bf(u0.z); v[3] = (short)f2bf(u0.w);
                v[4] = (short)f2bf(u1.x); v[5] = (short)f2bf(u1.y);
                v[6] = (short)f2bf(u1.z); v[7] = (short)f2bf(u1.w);
                *(short8*)&sA[row * 64 + col] = v;
            }
        } else {
#pragma unroll
            for (int i = 0; i < 4; ++i) {
                int c = t + i * 256, row = c >> 3, col = (c & 7) * 8;
                GLDS16(&((const ushort*)Ain)[(size_t)(m0 + row) * 768 + k0 + col],
                       &sA[row * 64 + col]);
            }
        }
        __syncthreads();
#pragma unroll
        for (int kk = 0; kk < 2; ++kk) {
            short8 af[4], bf[4];
#pragma unroll
            for (int mt = 0; mt < 4; ++mt)
                af[mt] = *(const short8*)&sA[(wm * 64 + mt * 16 + r) * 64 + kk * 32 + q * 8];
#pragma unroll
            for (int nt = 0; nt < 4; ++nt)
                bf[nt] = *(const short8*)&sB[(wn * 64 + nt * 16 + r) * 64 + kk * 32 + q * 8];
#pragma unroll
            for (int mt = 0; mt < 4; ++mt)
#pragma unroll
                for (int nt = 0; nt < 4; ++nt)
                    acc[mt][nt] = MFMA(af[mt], bf[nt], acc[mt][nt], 0, 0, 0);
        }
    }
#pragma unroll
    for (int nt = 0; nt < 4; ++nt) {
        int col = n0 + wn * 64 + nt * 16 + r;
        float bv = bias[col];
#pragma unroll
        for (int mt = 0; mt < 4; ++mt) {
            int rowb = m0 + wm * 64 + mt * 16 + q * 4;
#pragma unroll
            for (int j = 0; j < 4; ++j) {
                float v = acc[mt][nt][j] + bv;
                if (OUTBF) ((ushort*)out)[(size_t)(rowb + j) * 768 + col] = f2bf(v);
                else       ((float*)out)[(size_t)(rowb + j) * 768 + col] = v;
            }
        }
    }
}

// ---------------- recurrence: one WG per (dir, head, batch-16) ----------------
// 8 waves; wave w owns all 4 gates of hidden [8w,8w+8) (interleaved wcat).
// One barrier + one LDS round trip (double-buffered hbuf) per step.
__global__ __launch_bounds__(512) void lstm_rec(const ushort* __restrict__ ybf,
                                                const ushort* __restrict__ wcat,
                                                const float* __restrict__ bih_f,
                                                const float* __restrict__ bhh_f,
                                                const float* __restrict__ bih_b,
                                                const float* __restrict__ bhh_b,
                                                ushort* __restrict__ hs) {
    __shared__ __align__(16) ushort hbuf[2][16 * 64];  // XOR-swizzled 8-elem granules
    int t = threadIdx.x;
    int w = t >> 6, l = t & 63, r = l & 15, q = l >> 4;
    int b0 = blockIdx.x * 16, h = blockIdx.y, d = blockIdx.z;

    const ushort* wp = wcat + (size_t)(d * 12 + h) * 256 * 128;
    short8 by[2][2], bh[2][2];
#pragma unroll
    for (int nt = 0; nt < 2; ++nt)
#pragma unroll
        for (int kk = 0; kk < 2; ++kk) {
            int n = w * 32 + nt * 16 + r;
            by[nt][kk] = *(const short8*)&wp[n * 128 + kk * 32 + q * 8];
            bh[nt][kk] = *(const short8*)&wp[n * 128 + 64 + kk * 32 + q * 8];
        }
    const float* bih = d ? bih_b : bih_f;
    const float* bhh = d ? bhh_b : bhh_f;
    float bv[2];
#pragma unroll
    for (int nt = 0; nt < 2; ++nt) {
        int g = nt * 2 + (r >> 3), j = w * 8 + (r & 7);
        int gr = g * 768 + h * 64 + j;
        bv[nt] = bih[gr] + bhh[gr];
    }
    bool lo = (r < 8);
    int j0 = lo ? 0 : 2;
    float cst[2] = {0.f, 0.f};
    ((uint*)hbuf)[t] = 0u;  // zero hbuf[0] (h(-1)=0)

    const ushort* yrow = ybf + (size_t)(b0 + r) * 512 * 768 + h * 64 + q * 8;
    int s0 = d ? 511 : 0, st = d ? -1 : 1;

    // prologue: acc_y(step0) from y(s0); issue y(s0+st)
    short8 ya0 = *(const short8*)&yrow[s0 * 768];
    short8 ya1 = *(const short8*)&yrow[s0 * 768 + 32];
    f32x4 accy0 = (f32x4){bv[0], bv[0], bv[0], bv[0]};
    f32x4 accy1 = (f32x4){bv[1], bv[1], bv[1], bv[1]};
    accy0 = MFMA(ya0, by[0][0], accy0, 0, 0, 0);
    accy0 = MFMA(ya1, by[0][1], accy0, 0, 0, 0);
    accy1 = MFMA(ya0, by[1][0], accy1, 0, 0, 0);
    accy1 = MFMA(ya1, by[1][1], accy1, 0, 0, 0);
    short8 yb0 = *(const short8*)&yrow[(s0 + st) * 768];
    short8 yb1 = *(const short8*)&yrow[(s0 + st) * 768 + 32];
    __syncthreads();

    auto body = [&](int it, short8& yc0, short8& yc1, short8& yn0, short8& yn1) {
        int cur = it & 1;
        int s = s0 + it * st;
        // trailing hs write of h(it-1) from hbuf[cur] (off critical path)
        if (it > 0 && t < 256) {
            int rr = t >> 4, c16 = t & 15;
            int jj0 = c16 * 4, gg8 = c16 >> 1;
            uint2 v = *(const uint2*)&hbuf[cur][rr * 64 + ((gg8 ^ (rr & 7)) * 8 + (jj0 & 7))];
            *(uint2*)&hs[((size_t)(b0 + rr) * 512 + (s - st)) * 1536 + d * 768 + h * 64 + jj0] = v;
        }
        // A-frags of h(it-1)
        short8 ah0 = *(const short8*)&hbuf[cur][r * 64 + ((q ^ (r & 7)) * 8)];
        short8 ah1 = *(const short8*)&hbuf[cur][r * 64 + (((4 + q) ^ (r & 7)) * 8)];
        // issue y(it+2) loads (consumed at end of next body)
        if (it < 510) {
            yn0 = *(const short8*)&yrow[(s + 2 * st) * 768];
            yn1 = *(const short8*)&yrow[(s + 2 * st) * 768 + 32];
        }
        // gates = acc_y + h-part (2-deep chains)
        f32x4 a0 = accy0, a1 = accy1;
        a0 = MFMA(ah0, bh[0][0], a0, 0, 0, 0);
        a0 = MFMA(ah1, bh[0][1], a0, 0, 0, 0);
        a1 = MFMA(ah0, bh[1][0], a1, 0, 0, 0);
        a1 = MFMA(ah1, bh[1][1], a1, 0, 0, 0);
        // in-wave gate exchange: lane r<8 holds i(acc0),g(acc1); r>=8 holds f,o
        float e0[4], e1[4];
#pragma unroll
        for (int m = 0; m < 4; ++m) {
            e0[m] = __shfl_xor(a0[m], 8);
            e1[m] = __shfl_xor(a1[m], 8);
        }
        float hh[2];
#pragma unroll
        for (int k = 0; k < 2; ++k) {
            int m = j0 + k;
            float ip = lo ? a0[m] : e0[m];
            float fp = lo ? e0[m] : a0[m];
            float gp = lo ? a1[m] : e1[m];
            float op = lo ? e1[m] : a1[m];
            float ig = sigm(ip), fg = sigm(fp), og = sigm(op);
            float gg = tanh2(gp);
            float c = fg * cst[k] + ig * gg;
            cst[k] = c;
            hh[k] = og * tanh2(c);
        }
        // h(it) -> hbuf[cur^1]; lane handles rows 4q+j0, 4q+j0+1 of hidden j=w*8+(r&7)
        int nxt = cur ^ 1;
        int ro = 4 * q + j0;
        hbuf[nxt][ro * 64 + ((w ^ (ro & 7)) * 8) + (r & 7)] = f2bf(hh[0]);
        int ro1 = ro + 1;
        hbuf[nxt][ro1 * 64 + ((w ^ (ro1 & 7)) * 8) + (r & 7)] = f2bf(hh[1]);
        // acc_y(it+1) from y loaded one iteration ago (keeps MFMA pipe busy in update phase)
        accy0 = (f32x4){bv[0], bv[0], bv[0], bv[0]};
        accy1 = (f32x4){bv[1], bv[1], bv[1], bv[1]};
        accy0 = MFMA(yc0, by[0][0], accy0, 0, 0, 0);
        accy0 = MFMA(yc1, by[0][1], accy0, 0, 0, 0);
        accy1 = MFMA(yc0, by[1][0], accy1, 0, 0, 0);
        accy1 = MFMA(yc1, by[1][1], accy1, 0, 0, 0);
        __syncthreads();
    };

    for (int itb = 0; itb < 512; itb += 2) {
        body(itb, yb0, yb1, ya0, ya1);
        body(itb + 1, ya0, ya1, yb0, yb1);
    }
    // final h(511) lives in hbuf[0]
    if (t < 256) {
        int rr = t >> 4, c16 = t & 15;
        int jj0 = c16 * 4, gg8 = c16 >> 1;
        uint2 v = *(const uint2*)&hbuf[0][rr * 64 + ((gg8 ^ (rr & 7)) * 8 + (jj0 & 7))];
        *(uint2*)&hs[((size_t)(b0 + rr) * 512 + (s0 + 511 * st)) * 1536 + d * 768 + h * 64 + jj0] = v;
    }
}

// ---------------- head projection: per-head [32768,128] @ [64,128]^T ----------------
__global__ __launch_bounds__(256) void head_proj(const ushort* __restrict__ hs,
                                                 const ushort* __restrict__ wcat2,
                                                 const float* __restrict__ head_b,
                                                 float* __restrict__ out2,
                                                 ushort* __restrict__ out1b) {
    __shared__ __align__(16) ushort sA[128 * 128];
    __shared__ __align__(16) ushort sB[64 * 128];
    int t = threadIdx.x;
    int h = blockIdx.y, m0 = blockIdx.x * 128;
#pragma unroll
    for (int i = 0; i < 8; ++i) {
        int c = t + i * 256, row = c >> 4, c16 = c & 15;
        int dd = c16 >> 3, kc = (c16 & 7) * 8;
        GLDS16(&hs[(size_t)(m0 + row) * 1536 + dd * 768 + h * 64 + kc],
               &sA[row * 128 + c16 * 8]);
    }
#pragma unroll
    for (int i = 0; i < 4; ++i) {
        int c = t + i * 256, row = c >> 4, kc = (c & 15) * 8;
        GLDS16(&wcat2[(size_t)(h * 64 + row) * 128 + kc], &sB[row * 128 + kc]);
    }
    __syncthreads();
    int w = t >> 6, l = t & 63, r = l & 15, q = l >> 4;
    f32x4 acc[2][4];
#pragma unroll
    for (int a = 0; a < 2; ++a)
#pragma unroll
        for (int b = 0; b < 4; ++b) acc[a][b] = (f32x4){0.f, 0.f, 0.f, 0.f};
#pragma unroll
    for (int kk = 0; kk < 4; ++kk) {
        short8 af[2], bf[4];
#pragma unroll
        for (int mt = 0; mt < 2; ++mt)
            af[mt] = *(const short8*)&sA[(w * 32 + mt * 16 + r) * 128 + kk * 32 + q * 8];
#pragma unroll
        for (int nt = 0; nt < 4; ++nt)
            bf[nt] = *(const short8*)&sB[(nt * 16 + r) * 128 + kk * 32 + q * 8];
#pragma unroll
        for (int mt = 0; mt < 2; ++mt)
#pragma unroll
            for (int nt = 0; nt < 4; ++nt)
                acc[mt][nt] = MFMA(af[mt], bf[nt], acc[mt][nt], 0, 0, 0);
    }
#pragma unroll
    for (int nt = 0; nt < 4; ++nt) {
        int colg = h * 64 + nt * 16 + r;
        float bvv = head_b[colg];
#pragma unroll
        for (int mt = 0; mt < 2; ++mt) {
            int rowb = m0 + w * 32 + mt * 16 + q * 4;
#pragma unroll
            for (int j = 0; j < 4; ++j) {
                float v = acc[mt][nt][j] + bvv;
                out2[(size_t)(rowb + j) * 768 + colg] = v;
                out1b[(size_t)(rowb + j) * 768 + colg] = f2bf(v);
            }
        }
    }
}

extern "C" void kernel_launch(void* const* d_in, const int* in_sizes, int n_in,
                              void* d_out, int out_size, void* d_ws, size_t ws_size,
                              hipStream_t stream) {
    const float* x      = (const float*)d_in[0];
    const float* pre_w  = (const float*)d_in[1];
    const float* pre_b  = (const float*)d_in[2];
    const float* wih_f  = (const float*)d_in[3];
    const float* whh_f  = (const float*)d_in[4];
    const float* bih_f  = (const float*)d_in[5];
    const float* bhh_f  = (const float*)d_in[6];
    const float* wih_b  = (const float*)d_in[7];
    const float* whh_b  = (const float*)d_in[8];
    const float* bih_b  = (const float*)d_in[9];
    const float* bhh_b  = (const float*)d_in[10];
    const float* head_w = (const float*)d_in[11];
    const float* head_b = (const float*)d_in[12];
    const float* post_w = (const float*)d_in[13];
    const float* post_b = (const float*)d_in[14];

    char* ws = (char*)d_ws;
    ushort* ybf    = (ushort*)(ws + 0);              // 50331648 B (reused as out1b later)
    ushort* hsb    = (ushort*)(ws + 50331648);       // 100663296 B
    ushort* wcat   = (ushort*)(ws + 150994944);      // 1572864 B
    ushort* wcat2  = (ushort*)(ws + 152567808);      // 196608 B
    ushort* prewb  = (ushort*)(ws + 152764416);      // 1179648 B
    ushort* postwb = (ushort*)(ws + 153944064);      // 1179648 B

    float* outp  = (float*)d_out;            // out:      [32768,768] f32
    float* out2p = outp + 25165824;          // lstm_out: [32768,768] f32
    ushort* out1b = ybf;                     // bf16 copy of lstm_out (alias; ybf dead)

    prep_w<<<dim3(8064), dim3(256), 0, stream>>>(pre_w, post_w, wih_f, whh_f,
                                                 wih_b, whh_b, head_w,
                                                 prewb, postwb, wcat, wcat2);
    gemm_bt<1, 1><<<dim3(256, 6), dim3(256), 0, stream>>>(x, prewb, pre_b, (void*)ybf);
    lstm_rec<<<dim3(4, 12, 2), dim3(512), 0, stream>>>(ybf, wcat, bih_f, bhh_f,
                                                       bih_b, bhh_b, hsb);
    head_proj<<<dim3(256, 12), dim3(256), 0, stream>>>(hsb, wcat2, head_b, out2p, out1b);
    gemm_bt<0, 0><<<dim3(256, 6), dim3(256), 0, stream>>>(out1b, postwb, post_b, (void*)outp);
}

// Round 9
// 851.513 us; speedup vs baseline: 1.1856x; 1.0105x over previous
//
#include <hip/hip_runtime.h>
#include <stdint.h>

typedef __attribute__((ext_vector_type(8))) short short8;
typedef __attribute__((ext_vector_type(4))) float f32x4;

#define MFMA __builtin_amdgcn_mfma_f32_16x16x32_bf16

__device__ __forceinline__ ushort f2bf(float f) {
    uint u = __float_as_uint(f);
    u += 0x7FFF + ((u >> 16) & 1);
    return (ushort)(u >> 16);
}
__device__ __forceinline__ float sigm(float x) {
    return __builtin_amdgcn_rcpf(1.f + __expf(-x));
}
__device__ __forceinline__ float tanh2(float x) {
    return 1.f - 2.f * __builtin_amdgcn_rcpf(1.f + __expf(2.f * x));
}

// Raw workgroup barrier that drains ONLY lgkm (LDS) — unlike __syncthreads(),
// which emits s_waitcnt vmcnt(0) lgkmcnt(0) and forces every in-flight
// global load/store to complete (the ~900-cyc/step stall seen in R8).
__device__ __forceinline__ void wg_barrier_lds() {
    asm volatile("s_waitcnt lgkmcnt(0)" ::: "memory");
    __builtin_amdgcn_s_barrier();
    asm volatile("" ::: "memory");
}

// async global->LDS, 16B per lane; LDS dest must be wave-uniform-base + lane*16
#define GLDS16(g, l)                                                  \
    __builtin_amdgcn_global_load_lds(                                 \
        (__attribute__((address_space(1))) void*)(g),                 \
        (__attribute__((address_space(3))) void*)(l), 16, 0, 0)

// ---------------- prep: all weights -> bf16 / gathered layouts ----------------
// sections: prewb(589824) | postwb(589824) | wcat(786432) | wcat2(98304)
// wcat column order is GATE-INTERLEAVED: n -> gate g = 2*((n>>4)&1) + ((n>>3)&1),
// hidden j = (n>>5)*8 + (n&7). Wave w = n>>5 owns hidden [8w,8w+8) x all 4 gates.
__global__ void prep_w(const float* __restrict__ pre_w, const float* __restrict__ post_w,
                       const float* __restrict__ wih_f, const float* __restrict__ whh_f,
                       const float* __restrict__ wih_b, const float* __restrict__ whh_b,
                       const float* __restrict__ head_w,
                       ushort* __restrict__ prewb, ushort* __restrict__ postwb,
                       ushort* __restrict__ wcat, ushort* __restrict__ wcat2) {
    int i = blockIdx.x * 256 + threadIdx.x;
    const int NW = 589824;
    if (i < NW) { prewb[i] = f2bf(pre_w[i]); return; }
    i -= NW;
    if (i < NW) { postwb[i] = f2bf(post_w[i]); return; }
    i -= NW;
    if (i < 786432) {  // wcat [(d*12+h)*256+n][128]: k<64 -> wih, else whh
        int k = i & 127, n = (i >> 7) & 255, dh = i >> 15;
        int d = dh / 12, h = dh % 12;
        int g = ((n >> 4) & 1) * 2 + ((n >> 3) & 1);
        int j = ((n >> 5) << 3) + (n & 7);
        int gr = g * 768 + h * 64 + j;
        const float* wih = d ? wih_b : wih_f;
        const float* whh = d ? whh_b : whh_f;
        float v = (k < 64) ? wih[gr * 768 + h * 64 + k] : whh[gr * 768 + h * 64 + (k - 64)];
        wcat[i] = f2bf(v); return;
    }
    i -= 786432;
    {   // wcat2 [h*64+n][128]: k<64 fwd half, else bwd half
        int k = i & 127, n = (i >> 7) & 63, h = i >> 13;
        int row = h * 64 + n;
        float v = (k < 64) ? head_w[row * 1536 + h * 64 + k]
                           : head_w[row * 1536 + 768 + h * 64 + (k - 64)];
        wcat2[i] = f2bf(v);
    }
}

// ---------------- GEMM: C[32768,768] = A[32768,768] @ Bt[768,768]^T + bias ----------------
template<int INF32, int OUTBF>
__global__ __launch_bounds__(256) void gemm_bt(const void* __restrict__ Ain,
                                               const ushort* __restrict__ Bt,
                                               const float* __restrict__ bias,
                                               void* __restrict__ out) {
    __shared__ __align__(16) ushort sA[128 * 64];
    __shared__ __align__(16) ushort sB[128 * 64];
    int t = threadIdx.x;
    int m0 = blockIdx.x * 128, n0 = blockIdx.y * 128;
    int w = t >> 6, l = t & 63, r = l & 15, q = l >> 4;
    int wm = w >> 1, wn = w & 1;
    f32x4 acc[4][4];
#pragma unroll
    for (int a = 0; a < 4; ++a)
#pragma unroll
        for (int b = 0; b < 4; ++b) acc[a][b] = (f32x4){0.f, 0.f, 0.f, 0.f};

    for (int kt = 0; kt < 12; ++kt) {
        int k0 = kt * 64;
        __syncthreads();
#pragma unroll
        for (int i = 0; i < 4; ++i) {
            int c = t + i * 256, row = c >> 3, col = (c & 7) * 8;
            GLDS16(&Bt[(size_t)(n0 + row) * 768 + k0 + col], &sB[row * 64 + col]);
        }
        if (INF32) {
#pragma unroll
            for (int i = 0; i < 4; ++i) {
                int c = t + i * 256, row = c >> 3, col = (c & 7) * 8;
                const float* ap = (const float*)Ain + (size_t)(m0 + row) * 768 + k0 + col;
                float4 u0 = *(const float4*)ap;
                float4 u1 = *(const float4*)(ap + 4);
                short8 v;
                v[0] = (short)f2bf(u0.x); v[1] = (short)f2bf(u0.y);
                v[2] = (short)f2bf(u0.z); v[3] = (short)f2bf(u0.w);
                v[4] = (short)f2bf(u1.x); v[5] = (short)f2bf(u1.y);
                v[6] = (short)f2bf(u1.z); v[7] = (short)f2bf(u1.w);
                *(short8*)&sA[row * 64 + col] = v;
            }
        } else {
#pragma unroll
            for (int i = 0; i < 4; ++i) {
                int c = t + i * 256, row = c >> 3, col = (c & 7) * 8;
                GLDS16(&((const ushort*)Ain)[(size_t)(m0 + row) * 768 + k0 + col],
                       &sA[row * 64 + col]);
            }
        }
        __syncthreads();
#pragma unroll
        for (int kk = 0; kk < 2; ++kk) {
            short8 af[4], bf[4];
#pragma unroll
            for (int mt = 0; mt < 4; ++mt)
                af[mt] = *(const short8*)&sA[(wm * 64 + mt * 16 + r) * 64 + kk * 32 + q * 8];
#pragma unroll
            for (int nt = 0; nt < 4; ++nt)
                bf[nt] = *(const short8*)&sB[(wn * 64 + nt * 16 + r) * 64 + kk * 32 + q * 8];
#pragma unroll
            for (int mt = 0; mt < 4; ++mt)
#pragma unroll
                for (int nt = 0; nt < 4; ++nt)
                    acc[mt][nt] = MFMA(af[mt], bf[nt], acc[mt][nt], 0, 0, 0);
        }
    }
#pragma unroll
    for (int nt = 0; nt < 4; ++nt) {
        int col = n0 + wn * 64 + nt * 16 + r;
        float bv = bias[col];
#pragma unroll
        for (int mt = 0; mt < 4; ++mt) {
            int rowb = m0 + wm * 64 + mt * 16 + q * 4;
#pragma unroll
            for (int j = 0; j < 4; ++j) {
                float v = acc[mt][nt][j] + bv;
                if (OUTBF) ((ushort*)out)[(size_t)(rowb + j) * 768 + col] = f2bf(v);
                else       ((float*)out)[(size_t)(rowb + j) * 768 + col] = v;
            }
        }
    }
}

// ---------------- recurrence: one WG per (dir, head, batch-16) ----------------
// 8 waves; wave w owns all 4 gates of hidden [8w,8w+8) (interleaved wcat).
// One RAW barrier (lgkm-only drain) + one LDS round trip per step; y-prefetch
// global loads and hs stores stay in flight across barriers (T4 principle).
__global__ __launch_bounds__(512) void lstm_rec(const ushort* __restrict__ ybf,
                                                const ushort* __restrict__ wcat,
                                                const float* __restrict__ bih_f,
                                                const float* __restrict__ bhh_f,
                                                const float* __restrict__ bih_b,
                                                const float* __restrict__ bhh_b,
                                                ushort* __restrict__ hs) {
    __shared__ __align__(16) ushort hbuf[2][16 * 64];  // XOR-swizzled 8-elem granules
    int t = threadIdx.x;
    int w = t >> 6, l = t & 63, r = l & 15, q = l >> 4;
    int b0 = blockIdx.x * 16, h = blockIdx.y, d = blockIdx.z;

    const ushort* wp = wcat + (size_t)(d * 12 + h) * 256 * 128;
    short8 by[2][2], bh[2][2];
#pragma unroll
    for (int nt = 0; nt < 2; ++nt)
#pragma unroll
        for (int kk = 0; kk < 2; ++kk) {
            int n = w * 32 + nt * 16 + r;
            by[nt][kk] = *(const short8*)&wp[n * 128 + kk * 32 + q * 8];
            bh[nt][kk] = *(const short8*)&wp[n * 128 + 64 + kk * 32 + q * 8];
        }
    const float* bih = d ? bih_b : bih_f;
    const float* bhh = d ? bhh_b : bhh_f;
    float bv[2];
#pragma unroll
    for (int nt = 0; nt < 2; ++nt) {
        int g = nt * 2 + (r >> 3), j = w * 8 + (r & 7);
        int gr = g * 768 + h * 64 + j;
        bv[nt] = bih[gr] + bhh[gr];
    }
    bool lo = (r < 8);
    int j0 = lo ? 0 : 2;
    float cst[2] = {0.f, 0.f};
    ((uint*)hbuf)[t] = 0u;  // zero hbuf[0] (h(-1)=0)

    const ushort* yrow = ybf + (size_t)(b0 + r) * 512 * 768 + h * 64 + q * 8;
    int s0 = d ? 511 : 0, st = d ? -1 : 1;

    // prologue: acc_y(step0) from y(s0); issue y(s0+st)
    short8 ya0 = *(const short8*)&yrow[s0 * 768];
    short8 ya1 = *(const short8*)&yrow[s0 * 768 + 32];
    f32x4 accy0 = (f32x4){bv[0], bv[0], bv[0], bv[0]};
    f32x4 accy1 = (f32x4){bv[1], bv[1], bv[1], bv[1]};
    accy0 = MFMA(ya0, by[0][0], accy0, 0, 0, 0);
    accy0 = MFMA(ya1, by[0][1], accy0, 0, 0, 0);
    accy1 = MFMA(ya0, by[1][0], accy1, 0, 0, 0);
    accy1 = MFMA(ya1, by[1][1], accy1, 0, 0, 0);
    short8 yb0 = *(const short8*)&yrow[(s0 + st) * 768];
    short8 yb1 = *(const short8*)&yrow[(s0 + st) * 768 + 32];
    __syncthreads();   // once: hbuf[0] zero-init visible

    auto body = [&](int it, short8& yc0, short8& yc1, short8& yn0, short8& yn1) {
        int cur = it & 1;
        int s = s0 + it * st;
        // A-frags of h(it-1): critical-path ds_read issues first
        short8 ah0 = *(const short8*)&hbuf[cur][r * 64 + ((q ^ (r & 7)) * 8)];
        short8 ah1 = *(const short8*)&hbuf[cur][r * 64 + (((4 + q) ^ (r & 7)) * 8)];
        // issue y(it+2) loads early (consumed at end of next body; never drained)
        if (it < 510) {
            yn0 = *(const short8*)&yrow[(s + 2 * st) * 768];
            yn1 = *(const short8*)&yrow[(s + 2 * st) * 768 + 32];
        }
        // trailing hs write of h(it-1) from hbuf[cur] (off critical path)
        if (it > 0 && t < 256) {
            int rr = t >> 4, c16 = t & 15;
            int jj0 = c16 * 4, gg8 = c16 >> 1;
            uint2 v = *(const uint2*)&hbuf[cur][rr * 64 + ((gg8 ^ (rr & 7)) * 8 + (jj0 & 7))];
            *(uint2*)&hs[((size_t)(b0 + rr) * 512 + (s - st)) * 1536 + d * 768 + h * 64 + jj0] = v;
        }
        // gates = acc_y + h-part (2-deep chains)
        f32x4 a0 = accy0, a1 = accy1;
        a0 = MFMA(ah0, bh[0][0], a0, 0, 0, 0);
        a0 = MFMA(ah1, bh[0][1], a0, 0, 0, 0);
        a1 = MFMA(ah0, bh[1][0], a1, 0, 0, 0);
        a1 = MFMA(ah1, bh[1][1], a1, 0, 0, 0);
        // in-wave gate exchange: lane r<8 holds i(acc0),g(acc1); r>=8 holds f,o
        float e0[4], e1[4];
#pragma unroll
        for (int m = 0; m < 4; ++m) {
            e0[m] = __shfl_xor(a0[m], 8);
            e1[m] = __shfl_xor(a1[m], 8);
        }
        float hh[2];
#pragma unroll
        for (int k = 0; k < 2; ++k) {
            int m = j0 + k;
            float ip = lo ? a0[m] : e0[m];
            float fp = lo ? e0[m] : a0[m];
            float gp = lo ? a1[m] : e1[m];
            float op = lo ? e1[m] : a1[m];
            float ig = sigm(ip), fg = sigm(fp), og = sigm(op);
            float gg = tanh2(gp);
            float c = fg * cst[k] + ig * gg;
            cst[k] = c;
            hh[k] = og * tanh2(c);
        }
        // h(it) -> hbuf[cur^1]; lane handles rows 4q+j0, 4q+j0+1 of hidden j=w*8+(r&7)
        int nxt = cur ^ 1;
        int ro = 4 * q + j0;
        hbuf[nxt][ro * 64 + ((w ^ (ro & 7)) * 8) + (r & 7)] = f2bf(hh[0]);
        int ro1 = ro + 1;
        hbuf[nxt][ro1 * 64 + ((w ^ (ro1 & 7)) * 8) + (r & 7)] = f2bf(hh[1]);
        // acc_y(it+1) from y loaded one iteration ago (keeps MFMA pipe busy in update phase)
        accy0 = (f32x4){bv[0], bv[0], bv[0], bv[0]};
        accy1 = (f32x4){bv[1], bv[1], bv[1], bv[1]};
        accy0 = MFMA(yc0, by[0][0], accy0, 0, 0, 0);
        accy0 = MFMA(yc1, by[0][1], accy0, 0, 0, 0);
        accy1 = MFMA(yc0, by[1][0], accy1, 0, 0, 0);
        accy1 = MFMA(yc1, by[1][1], accy1, 0, 0, 0);
        wg_barrier_lds();   // lgkm-only drain: y-loads/hs-stores stay in flight
    };

    for (int itb = 0; itb < 512; itb += 2) {
        body(itb, yb0, yb1, ya0, ya1);
        body(itb + 1, ya0, ya1, yb0, yb1);
    }
    // final h(511) lives in hbuf[0]
    if (t < 256) {
        int rr = t >> 4, c16 = t & 15;
        int jj0 = c16 * 4, gg8 = c16 >> 1;
        uint2 v = *(const uint2*)&hbuf[0][rr * 64 + ((gg8 ^ (rr & 7)) * 8 + (jj0 & 7))];
        *(uint2*)&hs[((size_t)(b0 + rr) * 512 + (s0 + 511 * st)) * 1536 + d * 768 + h * 64 + jj0] = v;
    }
}

// ---------------- head projection: per-head [32768,128] @ [64,128]^T ----------------
__global__ __launch_bounds__(256) void head_proj(const ushort* __restrict__ hs,
                                                 const ushort* __restrict__ wcat2,
                                                 const float* __restrict__ head_b,
                                                 float* __restrict__ out2,
                                                 ushort* __restrict__ out1b) {
    __shared__ __align__(16) ushort sA[128 * 128];
    __shared__ __align__(16) ushort sB[64 * 128];
    int t = threadIdx.x;
    int h = blockIdx.y, m0 = blockIdx.x * 128;
#pragma unroll
    for (int i = 0; i < 8; ++i) {
        int c = t + i * 256, row = c >> 4, c16 = c & 15;
        int dd = c16 >> 3, kc = (c16 & 7) * 8;
        GLDS16(&hs[(size_t)(m0 + row) * 1536 + dd * 768 + h * 64 + kc],
               &sA[row * 128 + c16 * 8]);
    }
#pragma unroll
    for (int i = 0; i < 4; ++i) {
        int c = t + i * 256, row = c >> 4, kc = (c & 15) * 8;
        GLDS16(&wcat2[(size_t)(h * 64 + row) * 128 + kc], &sB[row * 128 + kc]);
    }
    __syncthreads();
    int w = t >> 6, l = t & 63, r = l & 15, q = l >> 4;
    f32x4 acc[2][4];
#pragma unroll
    for (int a = 0; a < 2; ++a)
#pragma unroll
        for (int b = 0; b < 4; ++b) acc[a][b] = (f32x4){0.f, 0.f, 0.f, 0.f};
#pragma unroll
    for (int kk = 0; kk < 4; ++kk) {
        short8 af[2], bf[4];
#pragma unroll
        for (int mt = 0; mt < 2; ++mt)
            af[mt] = *(const short8*)&sA[(w * 32 + mt * 16 + r) * 128 + kk * 32 + q * 8];
#pragma unroll
        for (int nt = 0; nt < 4; ++nt)
            bf[nt] = *(const short8*)&sB[(nt * 16 + r) * 128 + kk * 32 + q * 8];
#pragma unroll
        for (int mt = 0; mt < 2; ++mt)
#pragma unroll
            for (int nt = 0; nt < 4; ++nt)
                acc[mt][nt] = MFMA(af[mt], bf[nt], acc[mt][nt], 0, 0, 0);
    }
#pragma unroll
    for (int nt = 0; nt < 4; ++nt) {
        int colg = h * 64 + nt * 16 + r;
        float bvv = head_b[colg];
#pragma unroll
        for (int mt = 0; mt < 2; ++mt) {
            int rowb = m0 + w * 32 + mt * 16 + q * 4;
#pragma unroll
            for (int j = 0; j < 4; ++j) {
                float v = acc[mt][nt][j] + bvv;
                out2[(size_t)(rowb + j) * 768 + colg] = v;
                out1b[(size_t)(rowb + j) * 768 + colg] = f2bf(v);
            }
        }
    }
}

extern "C" void kernel_launch(void* const* d_in, const int* in_sizes, int n_in,
                              void* d_out, int out_size, void* d_ws, size_t ws_size,
                              hipStream_t stream) {
    const float* x      = (const float*)d_in[0];
    const float* pre_w  = (const float*)d_in[1];
    const float* pre_b  = (const float*)d_in[2];
    const float* wih_f  = (const float*)d_in[3];
    const float* whh_f  = (const float*)d_in[4];
    const float* bih_f  = (const float*)d_in[5];
    const float* bhh_f  = (const float*)d_in[6];
    const float* wih_b  = (const float*)d_in[7];
    const float* whh_b  = (const float*)d_in[8];
    const float* bih_b  = (const float*)d_in[9];
    const float* bhh_b  = (const float*)d_in[10];
    const float* head_w = (const float*)d_in[11];
    const float* head_b = (const float*)d_in[12];
    const float* post_w = (const float*)d_in[13];
    const float* post_b = (const float*)d_in[14];

    char* ws = (char*)d_ws;
    ushort* ybf    = (ushort*)(ws + 0);              // 50331648 B (reused as out1b later)
    ushort* hsb    = (ushort*)(ws + 50331648);       // 100663296 B
    ushort* wcat   = (ushort*)(ws + 150994944);      // 1572864 B
    ushort* wcat2  = (ushort*)(ws + 152567808);      // 196608 B
    ushort* prewb  = (ushort*)(ws + 152764416);      // 1179648 B
    ushort* postwb = (ushort*)(ws + 153944064);      // 1179648 B

    float* outp  = (float*)d_out;            // out:      [32768,768] f32
    float* out2p = outp + 25165824;          // lstm_out: [32768,768] f32
    ushort* out1b = ybf;                     // bf16 copy of lstm_out (alias; ybf dead)

    prep_w<<<dim3(8064), dim3(256), 0, stream>>>(pre_w, post_w, wih_f, whh_f,
                                                 wih_b, whh_b, head_w,
                                                 prewb, postwb, wcat, wcat2);
    gemm_bt<1, 1><<<dim3(256, 6), dim3(256), 0, stream>>>(x, prewb, pre_b, (void*)ybf);
    lstm_rec<<<dim3(4, 12, 2), dim3(512), 0, stream>>>(ybf, wcat, bih_f, bhh_f,
                                                       bih_b, bhh_b, hsb);
    head_proj<<<dim3(256, 12), dim3(256), 0, stream>>>(hsb, wcat2, head_b, out2p, out1b);
    gemm_bt<0, 0><<<dim3(256, 6), dim3(256), 0, stream>>>(out1b, postwb, post_b, (void*)outp);
}